// Round 5
// baseline (94.715 us; speedup 1.0000x reference)
//
#include <hip/hip_runtime.h>

typedef float v2f __attribute__((ext_vector_type(2)));
typedef float v4f __attribute__((ext_vector_type(4)));

#define IMG 512
#define TS  32
#define TPB 2                 // tiles per block
#define NBLK 1024             // 2048 tiles / 2

// LDS layouts (floats)
#define A_STR  56             // h tile [52][56]; gy=y0-10+r, gx=x0-12+c
#define BT_STR 46             // BT [56][46]: BT[c][by], by 0..41 (gy=y0-5+by)
#define E_STR  44             // E [42][44]: ey 0..41, ex 0..41; overlays Abuf
#define CT_STR 34             // CT [42][34]: CT[ex][oy], oy 0..31; overlays Bbuf
#define C_STR  48             // c tile [42][48]; gy=y0-5+r, gx=x0-8+cc (ex -> cc=ex+3)

__device__ __forceinline__ v2f lo2(v4f v) { return __builtin_shufflevector(v, v, 0, 1); }
__device__ __forceinline__ v2f hi2(v4f v) { return __builtin_shufflevector(v, v, 2, 3); }

// one float4 of the h halo tile (zero-padded), quad index idx in [0,728)
__device__ __forceinline__ v4f ldq(const float* __restrict__ hmap, size_t base,
                                   int x0, int y0, int idx) {
    int r = idx / 14, q = idx - r * 14;
    int gy = y0 - 10 + r, gx0 = x0 - 12 + 4 * q;
    v4f v = {0.f, 0.f, 0.f, 0.f};
    if ((unsigned)gy < IMG) {
        const float* hr = &hmap[base + ((size_t)gy << 9)];
        if (gx0 >= 0 && gx0 + 3 < IMG) {
            v = *(const v4f*)&hr[gx0];
        } else {
            if ((unsigned)(gx0 + 0) < IMG) v.x = hr[gx0 + 0];
            if ((unsigned)(gx0 + 1) < IMG) v.y = hr[gx0 + 1];
            if ((unsigned)(gx0 + 2) < IMG) v.z = hr[gx0 + 2];
            if ((unsigned)(gx0 + 3) < IMG) v.w = hr[gx0 + 3];
        }
    }
    return v;
}

// one float4 of the c tile (zero-padded), quad index idx in [0,504): 42 rows x 12 quads
__device__ __forceinline__ v4f ldc(const float* __restrict__ cmap, size_t base,
                                   int x0, int y0, int idx) {
    int r = idx / 12, q = idx - r * 12;
    int gy = y0 - 5 + r, gx0 = x0 - 8 + 4 * q;
    v4f v = {0.f, 0.f, 0.f, 0.f};
    if ((unsigned)gy < IMG) {
        const float* cr = &cmap[base + ((size_t)gy << 9)];
        if (gx0 >= 0 && gx0 + 3 < IMG) {
            v = *(const v4f*)&cr[gx0];
        } else {
            if ((unsigned)(gx0 + 0) < IMG) v.x = cr[gx0 + 0];
            if ((unsigned)(gx0 + 1) < IMG) v.y = cr[gx0 + 1];
            if ((unsigned)(gx0 + 2) < IMG) v.z = cr[gx0 + 2];
            if ((unsigned)(gx0 + 3) < IMG) v.w = cr[gx0 + 3];
        }
    }
    return v;
}

__global__ __launch_bounds__(256, 4) void marl_fused(
    const float* __restrict__ prob,
    const float* __restrict__ cmap,
    const float* __restrict__ hmap,
    float* __restrict__ out)
{
    __shared__ __align__(16) float Abuf[52 * A_STR];   // h tile, then E
    __shared__ __align__(16) float Bbuf[56 * BT_STR];  // BT, then CT
    __shared__ __align__(16) float Cbuf[42 * C_STR];   // c tile
    __shared__ float red[4];

    const float W[11] = {0.00881223f, 0.02714358f, 0.06511405f, 0.12164908f,
                         0.17699840f, 0.20056540f, 0.17699840f, 0.12164908f,
                         0.06511405f, 0.02714358f, 0.00881223f};
    v2f wv[11];
#pragma unroll
    for (int i = 0; i < 11; ++i) wv[i] = (v2f){W[i], W[i]};
    float w2 = 0.f;
#pragma unroll
    for (int i = 0; i < 11; ++i) w2 += W[i] * W[i];
    const float sumk2 = w2 * w2;
    const v2f z = {0.f, 0.f};

    const int tid = threadIdx.x;
    const int wk  = (tid & 63) * 4 + (tid >> 6);   // wave-balanced worker id
    const int i0 = tid, i1 = tid + 256, i2 = tid + 512;
    const int T0 = blockIdx.x * TPB;

    // epilogue mapping (P4): lanes vary ox
    const int ox0 = 2 * (tid & 15), oy0e = 2 * (tid >> 4);

    // per-tile epilogue registers (static via full unroll)
    v2f hv[TPB][2], pv[TPB][2];

    // ---- prologue: tile 0 — issue ALL global loads, stage h + c to LDS ----
    {
        const int b = T0 >> 8, r8 = T0 & 255;
        const int x0 = (r8 & 15) * TS, y0 = (r8 >> 4) * TS;
        const size_t base = (size_t)b << 18;
        v4f ha = ldq(hmap, base, x0, y0, i0);
        v4f hb = ldq(hmap, base, x0, y0, i1);
        v4f hc = (tid < 216) ? ldq(hmap, base, x0, y0, i2) : (v4f){0.f,0.f,0.f,0.f};
        v4f ca = ldc(cmap, base, x0, y0, i0);
        v4f cb = (tid < 248) ? ldc(cmap, base, x0, y0, i1) : (v4f){0.f,0.f,0.f,0.f};
#pragma unroll
        for (int h = 0; h < 2; ++h) {
            size_t rowb = base + ((size_t)(y0 + oy0e + h) << 9) + (x0 + ox0);
            hv[0][h] = *(const v2f*)&hmap[rowb];
            pv[0][h] = *(const v2f*)&prob[rowb];
        }
        { int r = i0 / 14, q = i0 - r * 14; *(v4f*)&Abuf[r * A_STR + 4 * q] = ha; }
        { int r = i1 / 14, q = i1 - r * 14; *(v4f*)&Abuf[r * A_STR + 4 * q] = hb; }
        if (tid < 216) { int r = i2 / 14, q = i2 - r * 14; *(v4f*)&Abuf[r * A_STR + 4 * q] = hc; }
        { int r = i0 / 12, q = i0 - r * 12; *(v4f*)&Cbuf[r * C_STR + 4 * q] = ca; }
        if (tid < 248) { int r = i1 / 12, q = i1 - r * 12; *(v4f*)&Cbuf[r * C_STR + 4 * q] = cb; }
    }
    __syncthreads();

    float partial = 0.f;
    v4f pfh0, pfh1, pfh2, pfc0, pfc1;   // tile-1 staging registers

#pragma unroll
    for (int t = 0; t < TPB; ++t) {
        const int T = T0 + t;
        const int r8 = T & 255;
        const int x0 = (r8 & 15) * TS, y0 = (r8 >> 4) * TS;

        // ---- P1: convY(h): Abuf[52][56] -> BT[56][46] (transposed) ----
        if (wk < 196) {
            int q = wk % 14, run = wk / 14;
            int by0 = 3 * run;
            v2f accLo[3] = {z, z, z}, accHi[3] = {z, z, z};
#pragma unroll
            for (int i = 0; i < 13; ++i) {
                v4f a = *(const v4f*)&Abuf[(by0 + i) * A_STR + 4 * q];
                v2f lo = lo2(a), hi = hi2(a);
#pragma unroll
                for (int r = 0; r < 3; ++r) {
                    int j = i - r;
                    if (j >= 0 && j < 11) { accLo[r] += wv[j] * lo; accHi[r] += wv[j] * hi; }
                }
            }
#pragma unroll
            for (int r = 0; r < 3; ++r) {
                int by = by0 + r;
                Bbuf[(4 * q + 0) * BT_STR + by] = accLo[r].x;
                Bbuf[(4 * q + 1) * BT_STR + by] = accLo[r].y;
                Bbuf[(4 * q + 2) * BT_STR + by] = accHi[r].x;
                Bbuf[(4 * q + 3) * BT_STR + by] = accHi[r].y;
            }
        }
        __syncthreads();

        // ---- P2: convX(BT) - c(LDS) -> E[42][44] (overlays Abuf) ----
        if (wk < 231) {
            int eq = wk % 11, p = wk / 11;
            int ex0 = 4 * eq, ey0 = 2 * p;
            v2f acc[4] = {z, z, z, z};
#pragma unroll
            for (int i = 0; i < 14; ++i) {
                v2f bb = *(const v2f*)&Bbuf[(ex0 + 2 + i) * BT_STR + ey0];
#pragma unroll
                for (int c = 0; c < 4; ++c) {
                    int j = i - c;
                    if (j >= 0 && j < 11) acc[c] += wv[j] * bb;
                }
            }
#pragma unroll
            for (int c = 0; c < 4; ++c) {
                int ex = ex0 + c;
                if (ex < 42) {
                    int gx = x0 - 5 + ex;
                    bool xin = (unsigned)gx < IMG;
#pragma unroll
                    for (int h = 0; h < 2; ++h) {
                        int gy = y0 - 5 + ey0 + h;
                        float v = 0.f;
                        if (xin && (unsigned)gy < IMG)
                            v = acc[c][h] - Cbuf[(ey0 + h) * C_STR + ex + 3];
                        Abuf[(ey0 + h) * E_STR + ex] = v;
                    }
                }
            }
        }
        __syncthreads();

        // ---- P3: issue tile-1 prefetch, then convY(E) -> CT[42][34] ----
        if (t + 1 < TPB) {
            const int Tn = T + 1;
            const int nb = Tn >> 8, nr8 = Tn & 255;
            const int nx0 = (nr8 & 15) * TS, ny0 = (nr8 >> 4) * TS;
            const size_t nbase = (size_t)nb << 18;
            pfh0 = ldq(hmap, nbase, nx0, ny0, i0);
            pfh1 = ldq(hmap, nbase, nx0, ny0, i1);
            if (tid < 216) pfh2 = ldq(hmap, nbase, nx0, ny0, i2);
            pfc0 = ldc(cmap, nbase, nx0, ny0, i0);
            if (tid < 248) pfc1 = ldc(cmap, nbase, nx0, ny0, i1);
#pragma unroll
            for (int h = 0; h < 2; ++h) {
                size_t rowb = nbase + ((size_t)(ny0 + oy0e + h) << 9) + (nx0 + ox0);
                hv[t + 1][h] = *(const v2f*)&hmap[rowb];
                pv[t + 1][h] = *(const v2f*)&prob[rowb];
            }
        }
        if (wk < 176) {
            int eq = wk % 11, run = wk / 11;
            int ex0 = 4 * eq, oyb = 2 * run;
            v2f accLo[2] = {z, z}, accHi[2] = {z, z};
#pragma unroll
            for (int i = 0; i < 12; ++i) {
                v4f e = *(const v4f*)&Abuf[(oyb + i) * E_STR + ex0];
                v2f lo = lo2(e), hi = hi2(e);
#pragma unroll
                for (int r = 0; r < 2; ++r) {
                    int j = i - r;
                    if (j >= 0 && j < 11) { accLo[r] += wv[j] * lo; accHi[r] += wv[j] * hi; }
                }
            }
#pragma unroll
            for (int r = 0; r < 2; ++r) {
                int oy = oyb + r;
                Bbuf[(ex0 + 0) * CT_STR + oy] = accLo[r].x;
                Bbuf[(ex0 + 1) * CT_STR + oy] = accLo[r].y;
                if (ex0 + 2 < 42) {
                    Bbuf[(ex0 + 2) * CT_STR + oy] = accHi[r].x;
                    Bbuf[(ex0 + 3) * CT_STR + oy] = accHi[r].y;
                }
            }
        }
        __syncthreads();

        // ---- P4: stage tile-1 h/c to LDS; convX(CT) -> corr + epilogue ----
        if (t + 1 < TPB) {
            { int r = i0 / 14, q = i0 - r * 14; *(v4f*)&Abuf[r * A_STR + 4 * q] = pfh0; }
            { int r = i1 / 14, q = i1 - r * 14; *(v4f*)&Abuf[r * A_STR + 4 * q] = pfh1; }
            if (tid < 216) { int r = i2 / 14, q = i2 - r * 14; *(v4f*)&Abuf[r * A_STR + 4 * q] = pfh2; }
            { int r = i0 / 12, q = i0 - r * 12; *(v4f*)&Cbuf[r * C_STR + 4 * q] = pfc0; }
            if (tid < 248) { int r = i1 / 12, q = i1 - r * 12; *(v4f*)&Cbuf[r * C_STR + 4 * q] = pfc1; }
        }
        {
            v2f acc[2] = {z, z};
#pragma unroll
            for (int i = 0; i < 12; ++i) {
                v2f ct = *(const v2f*)&Bbuf[(ox0 + i) * CT_STR + oy0e];
#pragma unroll
                for (int c = 0; c < 2; ++c) {
                    int j = i - c;
                    if (j >= 0 && j < 11) acc[c] += wv[j] * ct;
                }
            }
#pragma unroll
            for (int h = 0; h < 2; ++h) {
#pragma unroll
                for (int c = 0; c < 2; ++c) {
                    float h_ = hv[t][h][c], p_ = pv[t][h][c];
                    float logp = __logf(h_ > 0.5f ? p_ + 1e-8f : 1.f - p_ + 1e-8f);
                    float delta = 1.f - 2.f * h_;
                    partial += (2.f * delta * acc[c][h] + sumk2) * logp;
                }
            }
        }
        __syncthreads();
    }

    // ---- single reduction + one atomic per block ----
#pragma unroll
    for (int off = 32; off > 0; off >>= 1)
        partial += __shfl_down(partial, off, 64);
    if ((tid & 63) == 0) red[tid >> 6] = partial;
    __syncthreads();
    if (tid == 0) {
        float s = red[0] + red[1] + red[2] + red[3];
        atomicAdd(out, s * -0.125f);   // loss = -sum / B
    }
}

extern "C" void kernel_launch(void* const* d_in, const int* in_sizes, int n_in,
                              void* d_out, int out_size, void* d_ws, size_t ws_size,
                              hipStream_t stream) {
    const float* prob = (const float*)d_in[0];
    const float* cmap = (const float*)d_in[1];
    const float* hmap = (const float*)d_in[2];
    float* out = (float*)d_out;

    hipMemsetAsync(out, 0, sizeof(float), stream);

    marl_fused<<<dim3(NBLK), dim3(256), 0, stream>>>(prob, cmap, hmap, out);
}

// Round 6
// 92.057 us; speedup vs baseline: 1.0289x; 1.0289x over previous
//
#include <hip/hip_runtime.h>

typedef float v2f __attribute__((ext_vector_type(2)));
typedef float v4f __attribute__((ext_vector_type(4)));

#define IMG 512
#define TS  32
#define TPB 2                 // tiles per block
#define NBLK 1024             // 2048 tiles / 2

// LDS layouts (floats) — strides chosen for conflict-free lane patterns
#define A_STR  60             // h tile [52][60]; gy=y0-10+r, gx=x0-12+c (cols 0..55 used)
#define BT_STR 46             // BT [56][46]: BT[c][by], by 0..41 (gy=y0-5+by)
#define E_STR  64             // E [42][64]: XOR-swizzled cols; overlays Abuf
#define CT_STR 34             // CT [42][34]: CT[ex][oy], oy 0..31; overlays Bbuf
#define C_STR  49             // c tile [42][49]; gy=y0-5+r, gx=x0-8+cc (ex -> cc=ex+3)

__device__ __forceinline__ v2f lo2(v4f v) { return __builtin_shufflevector(v, v, 0, 1); }
__device__ __forceinline__ v2f hi2(v4f v) { return __builtin_shufflevector(v, v, 2, 3); }

// E column swizzle: spreads row-varying lane accesses across 8 bank-groups.
// Applied on BOTH write (P2) and read (P3); key is a pure function of row.
__device__ __forceinline__ int eswz(int row, int col) {
    return col ^ (((row >> 1) & 7) << 2);
}

// one float4 of the h halo tile (zero-padded), quad index idx in [0,728)
__device__ __forceinline__ v4f ldq(const float* __restrict__ hmap, size_t base,
                                   int x0, int y0, int idx) {
    int r = idx / 14, q = idx - r * 14;
    int gy = y0 - 10 + r, gx0 = x0 - 12 + 4 * q;
    v4f v = {0.f, 0.f, 0.f, 0.f};
    if ((unsigned)gy < IMG) {
        const float* hr = &hmap[base + ((size_t)gy << 9)];
        if (gx0 >= 0 && gx0 + 3 < IMG) {
            v = *(const v4f*)&hr[gx0];
        } else {
            if ((unsigned)(gx0 + 0) < IMG) v.x = hr[gx0 + 0];
            if ((unsigned)(gx0 + 1) < IMG) v.y = hr[gx0 + 1];
            if ((unsigned)(gx0 + 2) < IMG) v.z = hr[gx0 + 2];
            if ((unsigned)(gx0 + 3) < IMG) v.w = hr[gx0 + 3];
        }
    }
    return v;
}

// one float4 of the c tile (zero-padded), quad index idx in [0,504): 42 rows x 12 quads
__device__ __forceinline__ v4f ldc(const float* __restrict__ cmap, size_t base,
                                   int x0, int y0, int idx) {
    int r = idx / 12, q = idx - r * 12;
    int gy = y0 - 5 + r, gx0 = x0 - 8 + 4 * q;
    v4f v = {0.f, 0.f, 0.f, 0.f};
    if ((unsigned)gy < IMG) {
        const float* cr = &cmap[base + ((size_t)gy << 9)];
        if (gx0 >= 0 && gx0 + 3 < IMG) {
            v = *(const v4f*)&cr[gx0];
        } else {
            if ((unsigned)(gx0 + 0) < IMG) v.x = cr[gx0 + 0];
            if ((unsigned)(gx0 + 1) < IMG) v.y = cr[gx0 + 1];
            if ((unsigned)(gx0 + 2) < IMG) v.z = cr[gx0 + 2];
            if ((unsigned)(gx0 + 3) < IMG) v.w = cr[gx0 + 3];
        }
    }
    return v;
}

__global__ __launch_bounds__(256, 4) void marl_fused(
    const float* __restrict__ prob,
    const float* __restrict__ cmap,
    const float* __restrict__ hmap,
    float* __restrict__ out)
{
    __shared__ __align__(16) float Abuf[52 * A_STR];   // 3120 f: h tile, then E[42][64]
    __shared__ __align__(16) float Bbuf[56 * BT_STR];  // 2576 f: BT, then CT
    __shared__ __align__(16) float Cbuf[42 * C_STR];   // 2058 f: c tile (scalar-staged)
    __shared__ float red[4];

    const float W[11] = {0.00881223f, 0.02714358f, 0.06511405f, 0.12164908f,
                         0.17699840f, 0.20056540f, 0.17699840f, 0.12164908f,
                         0.06511405f, 0.02714358f, 0.00881223f};
    v2f wv[11];
#pragma unroll
    for (int i = 0; i < 11; ++i) wv[i] = (v2f){W[i], W[i]};
    float w2 = 0.f;
#pragma unroll
    for (int i = 0; i < 11; ++i) w2 += W[i] * W[i];
    const float sumk2 = w2 * w2;
    const v2f z = {0.f, 0.f};

    const int tid  = threadIdx.x;
    const int lane = tid & 63, wave = tid >> 6;
    // per-phase worker ids: contiguous chunk per wave (balanced AND lane-contiguous)
    const int wk1 = lane + wave * 49;   // P1: 196 workers, active lane<49
    const int wk2 = lane + wave * 58;   // P2: 231 workers, active lane<58 (wk2<231)
    const int wk3 = lane + wave * 44;   // P3: 176 workers, active lane<44
    const int i0 = tid, i1 = tid + 256, i2 = tid + 512;
    const int T0 = blockIdx.x * TPB;

    // P4/epilogue mapping: lanes vary oy-pair (CT read stride 2 -> conflict-free)
    const int oy0e = 2 * (tid & 15), ox0 = 2 * (tid >> 4);

    v2f hv[TPB][2], pv[TPB][2];

    // ---- prologue: tile 0 — issue ALL global loads, stage h + c to LDS ----
    {
        const int b = T0 >> 8, r8 = T0 & 255;
        const int x0 = (r8 & 15) * TS, y0 = (r8 >> 4) * TS;
        const size_t base = (size_t)b << 18;
        v4f ha = ldq(hmap, base, x0, y0, i0);
        v4f hb = ldq(hmap, base, x0, y0, i1);
        v4f hc = (tid < 216) ? ldq(hmap, base, x0, y0, i2) : (v4f){0.f,0.f,0.f,0.f};
        v4f ca = ldc(cmap, base, x0, y0, i0);
        v4f cb = (tid < 248) ? ldc(cmap, base, x0, y0, i1) : (v4f){0.f,0.f,0.f,0.f};
#pragma unroll
        for (int h = 0; h < 2; ++h) {
            size_t rowb = base + ((size_t)(y0 + oy0e + h) << 9) + (x0 + ox0);
            hv[0][h] = *(const v2f*)&hmap[rowb];
            pv[0][h] = *(const v2f*)&prob[rowb];
        }
        { int r = i0 / 14, q = i0 - r * 14; *(v4f*)&Abuf[r * A_STR + 4 * q] = ha; }
        { int r = i1 / 14, q = i1 - r * 14; *(v4f*)&Abuf[r * A_STR + 4 * q] = hb; }
        if (tid < 216) { int r = i2 / 14, q = i2 - r * 14; *(v4f*)&Abuf[r * A_STR + 4 * q] = hc; }
        { int r = i0 / 12, q = i0 - r * 12; float* d = &Cbuf[r * C_STR + 4 * q];
          d[0] = ca.x; d[1] = ca.y; d[2] = ca.z; d[3] = ca.w; }
        if (tid < 248) { int r = i1 / 12, q = i1 - r * 12; float* d = &Cbuf[r * C_STR + 4 * q];
          d[0] = cb.x; d[1] = cb.y; d[2] = cb.z; d[3] = cb.w; }
    }
    __syncthreads();

    float partial = 0.f;
    v4f pfh0, pfh1, pfh2, pfc0, pfc1;

#pragma unroll
    for (int t = 0; t < TPB; ++t) {
        const int T = T0 + t;
        const int r8 = T & 255;
        const int x0 = (r8 & 15) * TS, y0 = (r8 >> 4) * TS;

        // ---- P1: convY(h): Abuf[52][60] -> BT[56][46] (transposed) ----
        // lanes vary run (by): read stride 180f (order-8 banks), write stride 3f
        if (lane < 49) {
            int run = wk1 % 14, q = wk1 / 14;
            int by0 = 3 * run;
            v2f accLo[3] = {z, z, z}, accHi[3] = {z, z, z};
#pragma unroll
            for (int i = 0; i < 13; ++i) {
                v4f a = *(const v4f*)&Abuf[(by0 + i) * A_STR + 4 * q];
                v2f lo = lo2(a), hi = hi2(a);
#pragma unroll
                for (int r = 0; r < 3; ++r) {
                    int j = i - r;
                    if (j >= 0 && j < 11) { accLo[r] += wv[j] * lo; accHi[r] += wv[j] * hi; }
                }
            }
#pragma unroll
            for (int r = 0; r < 3; ++r) {
                int by = by0 + r;
                Bbuf[(4 * q + 0) * BT_STR + by] = accLo[r].x;
                Bbuf[(4 * q + 1) * BT_STR + by] = accLo[r].y;
                Bbuf[(4 * q + 2) * BT_STR + by] = accHi[r].x;
                Bbuf[(4 * q + 3) * BT_STR + by] = accHi[r].y;
            }
        }
        __syncthreads();

        // ---- P2: convX(BT) - c(LDS) -> E[42][64] swizzled (overlays Abuf) ----
        // lanes vary p (ey-pair): BT read stride 2f, C read stride 98f==2 mod 32
        if (lane < 58 && wk2 < 231) {
            int p = wk2 % 21, eq = wk2 / 21;
            int ex0 = 4 * eq, ey0 = 2 * p;
            v2f acc[4] = {z, z, z, z};
#pragma unroll
            for (int i = 0; i < 14; ++i) {
                v2f bb = *(const v2f*)&Bbuf[(ex0 + 2 + i) * BT_STR + ey0];
#pragma unroll
                for (int c = 0; c < 4; ++c) {
                    int j = i - c;
                    if (j >= 0 && j < 11) acc[c] += wv[j] * bb;
                }
            }
            int swz = (p & 7) << 2;   // == ((row>>1)&7)<<2 for rows 2p, 2p+1
#pragma unroll
            for (int c = 0; c < 4; ++c) {
                int ex = ex0 + c;
                if (ex < 42) {
                    int gx = x0 - 5 + ex;
                    bool xin = (unsigned)gx < IMG;
#pragma unroll
                    for (int h = 0; h < 2; ++h) {
                        int gy = y0 - 5 + ey0 + h;
                        float v = 0.f;
                        if (xin && (unsigned)gy < IMG)
                            v = acc[c][h] - Cbuf[(ey0 + h) * C_STR + ex + 3];
                        Abuf[(ey0 + h) * E_STR + (ex ^ swz)] = v;
                    }
                }
            }
        }
        __syncthreads();

        // ---- P3: issue tile-1 prefetch, then convY(E) -> CT[42][34] ----
        if (t + 1 < TPB) {
            const int Tn = T + 1;
            const int nb = Tn >> 8, nr8 = Tn & 255;
            const int nx0 = (nr8 & 15) * TS, ny0 = (nr8 >> 4) * TS;
            const size_t nbase = (size_t)nb << 18;
            pfh0 = ldq(hmap, nbase, nx0, ny0, i0);
            pfh1 = ldq(hmap, nbase, nx0, ny0, i1);
            if (tid < 216) pfh2 = ldq(hmap, nbase, nx0, ny0, i2);
            pfc0 = ldc(cmap, nbase, nx0, ny0, i0);
            if (tid < 248) pfc1 = ldc(cmap, nbase, nx0, ny0, i1);
#pragma unroll
            for (int h = 0; h < 2; ++h) {
                size_t rowb = nbase + ((size_t)(ny0 + oy0e + h) << 9) + (nx0 + ox0);
                hv[t + 1][h] = *(const v2f*)&hmap[rowb];
                pv[t + 1][h] = *(const v2f*)&prob[rowb];
            }
        }
        // lanes vary run (oy-pair): E read swizzle spreads rows; CT write stride 2f
        if (lane < 44) {
            int run = wk3 % 16, eq = wk3 / 16;
            int ex0 = 4 * eq, oyb = 2 * run;
            v2f accLo[2] = {z, z}, accHi[2] = {z, z};
#pragma unroll
            for (int i = 0; i < 12; ++i) {
                int row = oyb + i;
                v4f e = *(const v4f*)&Abuf[row * E_STR + eswz(row, ex0)];
                v2f lo = lo2(e), hi = hi2(e);
#pragma unroll
                for (int r = 0; r < 2; ++r) {
                    int j = i - r;
                    if (j >= 0 && j < 11) { accLo[r] += wv[j] * lo; accHi[r] += wv[j] * hi; }
                }
            }
#pragma unroll
            for (int r = 0; r < 2; ++r) {
                int oy = oyb + r;
                Bbuf[(ex0 + 0) * CT_STR + oy] = accLo[r].x;
                Bbuf[(ex0 + 1) * CT_STR + oy] = accLo[r].y;
                if (ex0 + 2 < 42) {
                    Bbuf[(ex0 + 2) * CT_STR + oy] = accHi[r].x;
                    Bbuf[(ex0 + 3) * CT_STR + oy] = accHi[r].y;
                }
            }
        }
        __syncthreads();

        // ---- P4: stage tile-1 h/c to LDS; convX(CT) -> corr + epilogue ----
        if (t + 1 < TPB) {
            { int r = i0 / 14, q = i0 - r * 14; *(v4f*)&Abuf[r * A_STR + 4 * q] = pfh0; }
            { int r = i1 / 14, q = i1 - r * 14; *(v4f*)&Abuf[r * A_STR + 4 * q] = pfh1; }
            if (tid < 216) { int r = i2 / 14, q = i2 - r * 14; *(v4f*)&Abuf[r * A_STR + 4 * q] = pfh2; }
            { int r = i0 / 12, q = i0 - r * 12; float* d = &Cbuf[r * C_STR + 4 * q];
              d[0] = pfc0.x; d[1] = pfc0.y; d[2] = pfc0.z; d[3] = pfc0.w; }
            if (tid < 248) { int r = i1 / 12, q = i1 - r * 12; float* d = &Cbuf[r * C_STR + 4 * q];
              d[0] = pfc1.x; d[1] = pfc1.y; d[2] = pfc1.z; d[3] = pfc1.w; }
        }
        {
            v2f acc[2] = {z, z};
#pragma unroll
            for (int i = 0; i < 12; ++i) {
                v2f ct = *(const v2f*)&Bbuf[(ox0 + i) * CT_STR + oy0e];
#pragma unroll
                for (int c = 0; c < 2; ++c) {
                    int j = i - c;
                    if (j >= 0 && j < 11) acc[c] += wv[j] * ct;
                }
            }
#pragma unroll
            for (int h = 0; h < 2; ++h) {
#pragma unroll
                for (int c = 0; c < 2; ++c) {
                    float h_ = hv[t][h][c], p_ = pv[t][h][c];
                    float logp = __logf(h_ > 0.5f ? p_ + 1e-8f : 1.f - p_ + 1e-8f);
                    float delta = 1.f - 2.f * h_;
                    partial += (2.f * delta * acc[c][h] + sumk2) * logp;
                }
            }
        }
        __syncthreads();
    }

    // ---- single reduction + one atomic per block ----
#pragma unroll
    for (int off = 32; off > 0; off >>= 1)
        partial += __shfl_down(partial, off, 64);
    if (lane == 0) red[wave] = partial;
    __syncthreads();
    if (tid == 0) {
        float s = red[0] + red[1] + red[2] + red[3];
        atomicAdd(out, s * -0.125f);   // loss = -sum / B
    }
}

extern "C" void kernel_launch(void* const* d_in, const int* in_sizes, int n_in,
                              void* d_out, int out_size, void* d_ws, size_t ws_size,
                              hipStream_t stream) {
    const float* prob = (const float*)d_in[0];
    const float* cmap = (const float*)d_in[1];
    const float* hmap = (const float*)d_in[2];
    float* out = (float*)d_out;

    hipMemsetAsync(out, 0, sizeof(float), stream);

    marl_fused<<<dim3(NBLK), dim3(256), 0, stream>>>(prob, cmap, hmap, out);
}